// Round 17
// baseline (663.619 us; speedup 1.0000x reference)
//
#include <hip/hip_runtime.h>
#include <stdint.h>

#define NNODE 2048
#define KI 32
#define DM 256

using short8 = __attribute__((ext_vector_type(8))) short;
using f32x4  = __attribute__((ext_vector_type(4))) float;

// ---- ws layout (bytes) ----
#define WU_OFF   1024            // u16 weights, 655360 elems
#define BIAS_OFF 1312768         // f32 bias, 2304

__device__ __forceinline__ float bf2f(uint16_t u){
  union { uint32_t i; float f; } v; v.i = ((uint32_t)u) << 16; return v.f;
}
__device__ __forceinline__ uint16_t f2bf(float f){
  union { float f; uint32_t i; } v; v.f = f;
  uint32_t x = v.i;
  return (uint16_t)((x + 0x7FFFu + ((x >> 16) & 1u)) >> 16);
}
__device__ __forceinline__ float read_f(const void* p, long idx, int fbf){
  return fbf ? bf2f(((const uint16_t*)p)[idx]) : ((const float*)p)[idx];
}

// ---------------- sniff -> ws flags ----------------
__global__ void sniff_kernel(const uint32_t* ni, const uint32_t* mask, int* flags){
  __shared__ int cnt[6];
  int t = threadIdx.x;
  if (t < 6) cnt[t] = 0;
  __syncthreads();
  {
    uint32_t u = ni[t];
    uint32_t lo = u & 0xFFFFu;
    uint32_t exl = (lo >> 7) & 0xFFu;
    if ((lo & 0x7FFFu) == 0u || (exl >= 100u && exl <= 140u)) atomicAdd(&cnt[0], 1);
  }
  if (t < 64){
    uint32_t u = mask[t];
    if (!(u == 0u || u == 1u)) atomicAdd(&cnt[1], 1);
    if (!(u == 0u || u == 0x3F800000u)) atomicAdd(&cnt[2], 1);
    uint32_t lo = u & 0xFFFFu, hi = u >> 16;
    if (!((lo == 0u || lo == 0x3F80u) && (hi == 0u || hi == 0x3F80u))) atomicAdd(&cnt[3], 1);
    if ((t & 1) && u != 0u) atomicAdd(&cnt[4], 1);
    if (!(t & 1) && u == 1u) atomicAdd(&cnt[5], 1);
  }
  __syncthreads();
  if (t == 0){
    flags[0] = (cnt[0] >= 160) ? 1 : 0;   // 1 = bf16 storage, 0 = f32
    int mk;
    if (cnt[1] == 0) mk = (cnt[4] == 0 && cnt[5] > 0) ? 4 : 0;
    else if (cnt[2] == 0) mk = 3;
    else if (cnt[3] == 0) mk = 2;
    else mk = 1;
    flags[1] = mk;
  }
}

// ---------------- prep: weights -> MFMA-fragment-ordered bf16 in ws ----------------
__global__ void prep_kernel(const void* fkW1, const void* fkb1, const void* fkW2, const void* fkb2,
                            const void* fvW1, const void* fvb1, const void* fvW2, const void* fvb2,
                            const void* qW, const void* kW, const void* vW,
                            const void* qb, const void* kb, const void* vb,
                            const void* oW, void* wsv){
  char* ws = (char*)wsv;
  const int fbf = ((const int*)ws)[0];
  uint16_t* wu = (uint16_t*)(ws + WU_OFF);
  float* bias = (float*)(ws + BIAS_OFF);
  const int total = 655360 + 2304;
  for (int o = blockIdx.x*blockDim.x + threadIdx.x; o < total; o += gridDim.x*blockDim.x){
    if (o < 655360){
      const void* src; long si;
      if (o < 131072){
        int t = o & 65535;
        src = (o < 65536) ? fkW1 : fvW1;
        int j = t & 7, l = (t >> 3) & 63, ks = (t >> 9) & 7, nt = t >> 12;
        int n = nt*16 + (l & 15);
        int k = ks*32 + ((l >> 4) << 3) + j;
        si = (long)k*256 + n;
      } else if (o < 393216){
        int oo = o - 131072;
        int t = oo & 131071;
        src = (oo < 131072) ? fkW2 : fvW2;
        int j = t & 7, l = (t >> 3) & 63, ks = (t >> 9) & 7, nt = t >> 12;
        int n = nt*16 + (l & 15);
        int k = ks*32 + ((l >> 4) << 3) + j;
        si = (long)k*512 + n;
      } else if (o < 524288){
        int oo = o - 393216;
        int t = oo & 65535;
        src = (oo < 65536) ? kW : vW;
        int j = t & 7, l = (t >> 3) & 63, ks = (t >> 9) & 7, nt = t >> 12;
        int n = nt*16 + (l & 15);       // n = h*64+e
        int k = ks*32 + ((l >> 4) << 3) + j;
        si = (long)(n >> 6)*16384 + (long)k*64 + (n & 63);
      } else if (o < 589824){
        int t = o - 524288;
        int col = t >> 8, d = t & 255;
        src = qW;
        si = (long)(col >> 6)*16384 + (long)d*64 + (col & 63);
      } else {
        int t = o - 589824;
        src = oW;
        si = t;
      }
      wu[o] = f2bf(read_f(src, si, fbf));
    } else {
      int bo = o - 655360;
      const void* src; long si;
      if (bo < 256){ src = fkb1; si = bo; }
      else if (bo < 768){ src = fkb2; si = bo - 256; }
      else if (bo < 1024){ src = fvb1; si = bo - 768; }
      else if (bo < 1536){ src = fvb2; si = bo - 1024; }
      else if (bo < 1792){ src = kb; si = bo - 1536; }
      else if (bo < 2048){ src = vb; si = bo - 1792; }
      else { src = qb; si = bo - 2048; }
      bias[bo] = read_f(src, si, fbf);
    }
  }
}

// ---------------- fragment helpers (verified layouts) ----------------
__device__ __forceinline__ int swz_off(int row, int col){
  return row*256 + ((col & 248) ^ ((row & 7) << 3)) + (col & 7);
}
__device__ __forceinline__ short8 lda(const uint16_t* buf, int mt, int ks, int lane){
  int row = mt*16 + (lane & 15);
  int kc  = ks*4 + (lane >> 4);
  int off = row*256 + (((kc << 3) ^ ((row & 7) << 3)));
  return *(const short8*)(buf + off);
}
__device__ __forceinline__ short8 ldb(const uint16_t* W, int nt, int ks, int lane){
  return *(const short8*)(W + ((((nt << 3) + ks) << 6) + lane) * 8);
}
__device__ __forceinline__ f32x4 mfma16(short8 a, short8 b, f32x4 c){
  return __builtin_amdgcn_mfma_f32_16x16x32_bf16(a, b, c, 0, 0, 0);
}

// h = silu(src @ W1 + b1) -> dst (both LDS, swizzled bf16)
__device__ __forceinline__ void gemm1_silu(const uint16_t* src, const uint16_t* W1, const float* b1,
                                           uint16_t* dst, int lane, int nh){
  const int cl = lane & 15, kg = lane >> 4;
  f32x4 acc[2][4];
  #pragma unroll
  for (int i = 0; i < 4; i++){
    float bb = b1[(nh*4 + i)*16 + cl];
    f32x4 c = {bb,bb,bb,bb};
    acc[0][i] = c; acc[1][i] = c;
  }
  #pragma unroll
  for (int ks = 0; ks < 8; ks++){
    short8 a0 = lda(src, 0, ks, lane);
    short8 a1 = lda(src, 1, ks, lane);
    #pragma unroll
    for (int i = 0; i < 4; i++){
      short8 bv = ldb(W1, nh*4 + i, ks, lane);
      acc[0][i] = mfma16(a0, bv, acc[0][i]);
      acc[1][i] = mfma16(a1, bv, acc[1][i]);
    }
  }
  #pragma unroll
  for (int m = 0; m < 2; m++){
    int rowb = m*16 + kg*4;
    #pragma unroll
    for (int i = 0; i < 4; i++){
      int col = (nh*4 + i)*16 + cl;
      #pragma unroll
      for (int r = 0; r < 4; r++){
        float v = acc[m][i][r];
        dst[swz_off(rowb + r, col)] = f2bf(v / (1.0f + __expf(-v)));
      }
    }
  }
}

// gb = h @ W2 + b2 ; dst = gamma*xj + beta (xj in LDS, swizzled bf16)
__device__ __forceinline__ void gemm2_film(const uint16_t* src, const uint16_t* W2, const float* b2,
                                           const uint16_t* xj, uint16_t* dst, int lane, int nh){
  const int cl = lane & 15, kg = lane >> 4;
  #pragma unroll
  for (int ch = 0; ch < 2; ch++){
    f32x4 ag[2][2], ab[2][2];
    #pragma unroll
    for (int j = 0; j < 2; j++){
      int dt = nh*4 + ch*2 + j;
      float bg = b2[dt*16 + cl];
      float bb = b2[(16 + dt)*16 + cl];
      f32x4 cg = {bg,bg,bg,bg}, cb = {bb,bb,bb,bb};
      ag[0][j] = cg; ag[1][j] = cg; ab[0][j] = cb; ab[1][j] = cb;
    }
    #pragma unroll
    for (int ks = 0; ks < 8; ks++){
      short8 a0 = lda(src, 0, ks, lane);
      short8 a1 = lda(src, 1, ks, lane);
      #pragma unroll
      for (int j = 0; j < 2; j++){
        int dt = nh*4 + ch*2 + j;
        short8 bg = ldb(W2, dt, ks, lane);
        short8 bb = ldb(W2, 16 + dt, ks, lane);
        ag[0][j] = mfma16(a0, bg, ag[0][j]);
        ag[1][j] = mfma16(a1, bg, ag[1][j]);
        ab[0][j] = mfma16(a0, bb, ab[0][j]);
        ab[1][j] = mfma16(a1, bb, ab[1][j]);
      }
    }
    #pragma unroll
    for (int m = 0; m < 2; m++){
      int rowb = m*16 + kg*4;
      #pragma unroll
      for (int j = 0; j < 2; j++){
        int d = (nh*4 + ch*2 + j)*16 + cl;
        #pragma unroll
        for (int r = 0; r < 4; r++){
          int row = rowb + r;
          float x = bf2f(xj[swz_off(row, d)]);
          dst[swz_off(row, d)] = f2bf(ag[m][j][r] * x + ab[m][j][r]);
        }
      }
    }
  }
}

// K = kin @ k_proj + kb ; wave nh covers head nh; S[row][nh] = Q . K
__device__ __forceinline__ void gemm3_scores(const uint16_t* src, const uint16_t* W, const float* bs,
                                             const float* sQ, float (*sS)[4], int lane, int nh){
  const int cl = lane & 15, kg = lane >> 4;
  f32x4 acc[2][4];
  #pragma unroll
  for (int i = 0; i < 4; i++){
    float bb = bs[(nh*4 + i)*16 + cl];
    f32x4 c = {bb,bb,bb,bb};
    acc[0][i] = c; acc[1][i] = c;
  }
  #pragma unroll
  for (int ks = 0; ks < 8; ks++){
    short8 a0 = lda(src, 0, ks, lane);
    short8 a1 = lda(src, 1, ks, lane);
    #pragma unroll
    for (int i = 0; i < 4; i++){
      short8 bv = ldb(W, nh*4 + i, ks, lane);
      acc[0][i] = mfma16(a0, bv, acc[0][i]);
      acc[1][i] = mfma16(a1, bv, acc[1][i]);
    }
  }
  #pragma unroll
  for (int m = 0; m < 2; m++){
    int rowb = m*16 + kg*4;
    float p0=0.f, p1=0.f, p2=0.f, p3=0.f;
    #pragma unroll
    for (int i = 0; i < 4; i++){
      float qv = sQ[(nh*4 + i)*16 + cl];
      p0 += acc[m][i][0]*qv; p1 += acc[m][i][1]*qv;
      p2 += acc[m][i][2]*qv; p3 += acc[m][i][3]*qv;
    }
    float pr[4] = {p0, p1, p2, p3};
    #pragma unroll
    for (int r = 0; r < 4; r++){
      float v = pr[r];
      v += __shfl_xor(v, 1, 16);
      v += __shfl_xor(v, 2, 16);
      v += __shfl_xor(v, 4, 16);
      v += __shfl_xor(v, 8, 16);
      if (cl == 0) sS[rowb + r][nh] = v;
    }
  }
}

// V = vin @ v_proj + vb -> dst (swizzled bf16)
__device__ __forceinline__ void gemm3_store(const uint16_t* src, const uint16_t* W, const float* bs,
                                            uint16_t* dst, int lane, int nh){
  const int cl = lane & 15, kg = lane >> 4;
  f32x4 acc[2][4];
  #pragma unroll
  for (int i = 0; i < 4; i++){
    float bb = bs[(nh*4 + i)*16 + cl];
    f32x4 c = {bb,bb,bb,bb};
    acc[0][i] = c; acc[1][i] = c;
  }
  #pragma unroll
  for (int ks = 0; ks < 8; ks++){
    short8 a0 = lda(src, 0, ks, lane);
    short8 a1 = lda(src, 1, ks, lane);
    #pragma unroll
    for (int i = 0; i < 4; i++){
      short8 bv = ldb(W, nh*4 + i, ks, lane);
      acc[0][i] = mfma16(a0, bv, acc[0][i]);
      acc[1][i] = mfma16(a1, bv, acc[1][i]);
    }
  }
  #pragma unroll
  for (int m = 0; m < 2; m++){
    int rowb = m*16 + kg*4;
    #pragma unroll
    for (int i = 0; i < 4; i++){
      int col = (nh*4 + i)*16 + cl;
      #pragma unroll
      for (int r = 0; r < 4; r++)
        dst[swz_off(rowb + r, col)] = f2bf(acc[m][i][r]);
    }
  }
}

// ---------------- fused kernel: 1 block = 1 node, all-LDS, 6 barriers ----------------
__launch_bounds__(256, 1)
__global__ void fused_kernel(const void* nodes_i, const void* edges, const void* nodes_j, const void* maskp,
                             const void* wsv, float* out)
{
  const char* ws = (const char*)wsv;
  const int* flags = (const int*)ws;
  const int fbf = flags[0], mk = flags[1];
  const uint16_t* wu = (const uint16_t*)(ws + WU_OFF);
  const float* bias = (const float*)(ws + BIAS_OFF);
  const uint16_t* W1k = wu;
  const uint16_t* W1v = wu + 65536;
  const uint16_t* W2k = wu + 131072;
  const uint16_t* W2v = wu + 262144;
  const uint16_t* KBw = wu + 393216;
  const uint16_t* VBw = wu + 458752;
  const uint16_t* QBt = wu + 524288;
  const uint16_t* WoB = wu + 589824;
  const float* b1k = bias;
  const float* b2k = bias + 256;
  const float* b1v = bias + 768;
  const float* b2v = bias + 1024;
  const float* kbb = bias + 1536;
  const float* vbb = bias + 1792;
  const float* qbb = bias + 2048;

  __shared__ __align__(16) uint16_t bufE[KI*DM];   // E -> kin
  __shared__ __align__(16) uint16_t bufXJ[KI*DM];  // nodes_j (bf16, swizzled)
  __shared__ __align__(16) uint16_t bufA[KI*DM];   // h_k -> vin
  __shared__ __align__(16) uint16_t bufB[KI*DM];   // h_v -> V
  __shared__ float sQ[DM];
  __shared__ float sNI[DM];
  __shared__ float sS[KI][4];
  __shared__ float sP[KI][4];
  __shared__ float sO[DM];

  const int tid = threadIdx.x;
  const int lane = tid & 63;
  const int nh = tid >> 6;     // wave id = N-quarter / head
  const int b = blockIdx.x;
  const int z = b >> 11;
  const int n = b & 2047;
  const long ebase = ((long)(z*NNODE + n)) * (KI*DM);
  const long nbase = ((long)(z*NNODE + n)) * DM;

  // P0: stage nodes_i row + E + xj tiles (bf16, swizzled)
  sNI[tid] = read_f(nodes_i, nbase + tid, fbf);
  if (fbf){
    const uint16_t* xp = (const uint16_t*)nodes_j;
    const uint16_t* ep = (const uint16_t*)edges;
    for (int c = tid; c < 2048; c += 256){
      int sel = c >> 10, cc = c & 1023;
      int row = cc >> 5, kc = cc & 31;
      const uint16_t* src = sel ? ep : xp;
      uint16_t* dst = sel ? bufE : bufXJ;
      short8 v = *(const short8*)(src + ebase + row*256 + kc*8);
      *(short8*)(dst + row*256 + (((kc << 3) ^ ((row & 7) << 3)))) = v;
    }
  } else {
    const float* xp = (const float*)nodes_j;
    const float* ep = (const float*)edges;
    for (int c = tid; c < 2048; c += 256){
      int sel = c >> 10, cc = c & 1023;
      int row = cc >> 5, kc = cc & 31;
      const float* src = (sel ? ep : xp) + ebase + row*256 + kc*8;
      uint16_t* dst = sel ? bufE : bufXJ;
      f32x4 x0 = *(const f32x4*)src;
      f32x4 x1 = *(const f32x4*)(src + 4);
      short8 v;
      v[0]=(short)f2bf(x0[0]); v[1]=(short)f2bf(x0[1]); v[2]=(short)f2bf(x0[2]); v[3]=(short)f2bf(x0[3]);
      v[4]=(short)f2bf(x1[0]); v[5]=(short)f2bf(x1[1]); v[6]=(short)f2bf(x1[2]); v[7]=(short)f2bf(x1[3]);
      *(short8*)(dst + row*256 + (((kc << 3) ^ ((row & 7) << 3)))) = v;
    }
  }
  __syncthreads();                               // B1

  // P1: Q projection + gemm1 K then gemm1 V (sequential, low register pressure)
  {
    const uint16_t* wrow = QBt + tid*256;
    float a = qbb[tid];
    for (int d = 0; d < 256; d += 8){
      short8 wv = *(const short8*)(wrow + d);
      #pragma unroll
      for (int j = 0; j < 8; j++)
        a += sNI[d + j] * bf2f((uint16_t)wv[j]);
    }
    sQ[tid] = a * 0.125f;
  }
  gemm1_silu(bufE, W1k, b1k, bufA, lane, nh);
  __builtin_amdgcn_sched_barrier(0);             // keep K/V passes from interleaving
  gemm1_silu(bufE, W1v, b1v, bufB, lane, nh);
  __syncthreads();                               // B2  (E dead)

  // P2: gemm2 K: kin = gamma_k*xj + beta_k -> bufE
  gemm2_film(bufA, W2k, b2k, bufXJ, bufE, lane, nh);
  __syncthreads();                               // B3  (h_k dead)

  // P3: scores(kin) || gemm2 V: vin -> bufA
  gemm3_scores(bufE, KBw, kbb, sQ, sS, lane, nh);
  __builtin_amdgcn_sched_barrier(0);
  gemm2_film(bufB, W2v, b2v, bufXJ, bufA, lane, nh);
  __syncthreads();                               // B4  (h_v, xj dead)

  // P4: softmax (threads 0-127) || V = vin @ VB -> bufB
  gemm3_store(bufA, VBw, vbb, bufB, lane, nh);
  if (tid < 128){
    int h2 = tid >> 5, k2 = tid & 31;
    long mi = (long)(z*NNODE + n)*KI + k2;
    bool mval;
    if (mk == 0)      mval = ((const int*)maskp)[mi] != 0;
    else if (mk == 1) mval = ((const unsigned char*)maskp)[mi] != 0;
    else if (mk == 2) mval = ((const uint16_t*)maskp)[mi] != 0;
    else if (mk == 4) mval = ((const int*)maskp)[mi*2] != 0;
    else              mval = ((const float*)maskp)[mi] != 0.0f;
    unsigned long long bal = __ballot(mval);
    unsigned int gm = (unsigned int)(bal >> (tid & 32));
    bool anyT = (gm != 0u);
    float s = sS[k2][h2];
    if (anyT && !mval) s = -1e30f;
    float mx = s;
    mx = fmaxf(mx, __shfl_xor(mx, 16, 32));
    mx = fmaxf(mx, __shfl_xor(mx,  8, 32));
    mx = fmaxf(mx, __shfl_xor(mx,  4, 32));
    mx = fmaxf(mx, __shfl_xor(mx,  2, 32));
    mx = fmaxf(mx, __shfl_xor(mx,  1, 32));
    float e = __expf(s - mx);
    float su = e;
    su += __shfl_xor(su, 16, 32);
    su += __shfl_xor(su,  8, 32);
    su += __shfl_xor(su,  4, 32);
    su += __shfl_xor(su,  2, 32);
    su += __shfl_xor(su,  1, 32);
    sP[k2][h2] = e / su;
  }
  __syncthreads();                               // B5

  // P5: PV: col c = tid; sO[e*4+h]
  {
    int h = tid >> 6;
    float a = 0.0f;
    #pragma unroll 4
    for (int k = 0; k < KI; k++)
      a += sP[k][h] * bf2f(bufB[swz_off(k, tid)]);
    sO[(tid & 63)*4 + h] = a;
  }
  __syncthreads();                               // B6

  // P6: out projection: y[d=tid] = sum_m sO[m] * Wo[d][m]
  {
    const uint16_t* wrow = WoB + tid*256;
    float a = 0.0f;
    for (int m8 = 0; m8 < 256; m8 += 8){
      short8 wv = *(const short8*)(wrow + m8);
      #pragma unroll
      for (int j = 0; j < 8; j++)
        a += sO[m8 + j] * bf2f((uint16_t)wv[j]);
    }
    out[nbase + tid] = a;
  }
}

extern "C" void kernel_launch(void* const* d_in, const int* in_sizes, int n_in,
                              void* d_out, int out_size, void* d_ws, size_t ws_size,
                              hipStream_t stream){
  // inputs: 0 nodes_i, 1 edges, 2 nodes_j, 3 nbr_mask, 4 fk_W1, 5 fk_b1,
  // 6 fk_W2, 7 fk_b2, 8 fv_W1, 9 fv_b1, 10 fv_W2, 11 fv_b2, 12 q_proj,
  // 13 k_proj, 14 v_proj, 15 q_bias, 16 k_bias, 17 v_bias, 18 out_W
  int* flags = (int*)d_ws;
  sniff_kernel<<<1, 256, 0, stream>>>((const uint32_t*)d_in[0], (const uint32_t*)d_in[3], flags);
  prep_kernel<<<1024, 256, 0, stream>>>(d_in[4], d_in[5], d_in[6], d_in[7],
                                        d_in[8], d_in[9], d_in[10], d_in[11],
                                        d_in[12], d_in[13], d_in[14],
                                        d_in[15], d_in[16], d_in[17],
                                        d_in[18], d_ws);
  fused_kernel<<<2*NNODE, 256, 0, stream>>>(d_in[0], d_in[1], d_in[2], d_in[3], d_ws, (float*)d_out);
}

// Round 18
// 635.838 us; speedup vs baseline: 1.0437x; 1.0437x over previous
//
#include <hip/hip_runtime.h>
#include <stdint.h>

#define NNODE 2048
#define KI 32
#define DM 256

using short8 = __attribute__((ext_vector_type(8))) short;
using f32x4  = __attribute__((ext_vector_type(4))) float;

// ---- ws layout (bytes) ----
#define WU_OFF   1024            // u16 weights, 655360 elems
#define BIAS_OFF 1312768         // f32 bias, 2304

__device__ __forceinline__ float bf2f(uint16_t u){
  union { uint32_t i; float f; } v; v.i = ((uint32_t)u) << 16; return v.f;
}
__device__ __forceinline__ uint16_t f2bf(float f){
  union { float f; uint32_t i; } v; v.f = f;
  uint32_t x = v.i;
  return (uint16_t)((x + 0x7FFFu + ((x >> 16) & 1u)) >> 16);
}
__device__ __forceinline__ float read_f(const void* p, long idx, int fbf){
  return fbf ? bf2f(((const uint16_t*)p)[idx]) : ((const float*)p)[idx];
}

// ---------------- sniff -> ws flags ----------------
__global__ void sniff_kernel(const uint32_t* ni, const uint32_t* mask, int* flags){
  __shared__ int cnt[6];
  int t = threadIdx.x;
  if (t < 6) cnt[t] = 0;
  __syncthreads();
  {
    uint32_t u = ni[t];
    uint32_t lo = u & 0xFFFFu;
    uint32_t exl = (lo >> 7) & 0xFFu;
    if ((lo & 0x7FFFu) == 0u || (exl >= 100u && exl <= 140u)) atomicAdd(&cnt[0], 1);
  }
  if (t < 64){
    uint32_t u = mask[t];
    if (!(u == 0u || u == 1u)) atomicAdd(&cnt[1], 1);
    if (!(u == 0u || u == 0x3F800000u)) atomicAdd(&cnt[2], 1);
    uint32_t lo = u & 0xFFFFu, hi = u >> 16;
    if (!((lo == 0u || lo == 0x3F80u) && (hi == 0u || hi == 0x3F80u))) atomicAdd(&cnt[3], 1);
    if ((t & 1) && u != 0u) atomicAdd(&cnt[4], 1);
    if (!(t & 1) && u == 1u) atomicAdd(&cnt[5], 1);
  }
  __syncthreads();
  if (t == 0){
    flags[0] = (cnt[0] >= 160) ? 1 : 0;   // 1 = bf16 storage, 0 = f32
    int mk;
    if (cnt[1] == 0) mk = (cnt[4] == 0 && cnt[5] > 0) ? 4 : 0;
    else if (cnt[2] == 0) mk = 3;
    else if (cnt[3] == 0) mk = 2;
    else mk = 1;
    flags[1] = mk;
  }
}

// ---------------- prep: weights -> MFMA-fragment-ordered bf16 in ws ----------------
__global__ void prep_kernel(const void* fkW1, const void* fkb1, const void* fkW2, const void* fkb2,
                            const void* fvW1, const void* fvb1, const void* fvW2, const void* fvb2,
                            const void* qW, const void* kW, const void* vW,
                            const void* qb, const void* kb, const void* vb,
                            const void* oW, void* wsv){
  char* ws = (char*)wsv;
  const int fbf = ((const int*)ws)[0];
  uint16_t* wu = (uint16_t*)(ws + WU_OFF);
  float* bias = (float*)(ws + BIAS_OFF);
  const int total = 655360 + 2304;
  for (int o = blockIdx.x*blockDim.x + threadIdx.x; o < total; o += gridDim.x*blockDim.x){
    if (o < 655360){
      const void* src; long si;
      if (o < 131072){
        int t = o & 65535;
        src = (o < 65536) ? fkW1 : fvW1;
        int j = t & 7, l = (t >> 3) & 63, ks = (t >> 9) & 7, nt = t >> 12;
        int n = nt*16 + (l & 15);
        int k = ks*32 + ((l >> 4) << 3) + j;
        si = (long)k*256 + n;
      } else if (o < 393216){
        int oo = o - 131072;
        int t = oo & 131071;
        src = (oo < 131072) ? fkW2 : fvW2;
        int j = t & 7, l = (t >> 3) & 63, ks = (t >> 9) & 7, nt = t >> 12;
        int n = nt*16 + (l & 15);
        int k = ks*32 + ((l >> 4) << 3) + j;
        si = (long)k*512 + n;
      } else if (o < 524288){
        int oo = o - 393216;
        int t = oo & 65535;
        src = (oo < 65536) ? kW : vW;
        int j = t & 7, l = (t >> 3) & 63, ks = (t >> 9) & 7, nt = t >> 12;
        int n = nt*16 + (l & 15);       // n = h*64+e
        int k = ks*32 + ((l >> 4) << 3) + j;
        si = (long)(n >> 6)*16384 + (long)k*64 + (n & 63);
      } else if (o < 589824){
        int t = o - 524288;
        int col = t >> 8, d = t & 255;
        src = qW;
        si = (long)(col >> 6)*16384 + (long)d*64 + (col & 63);
      } else {
        int t = o - 589824;
        src = oW;
        si = t;
      }
      wu[o] = f2bf(read_f(src, si, fbf));
    } else {
      int bo = o - 655360;
      const void* src; long si;
      if (bo < 256){ src = fkb1; si = bo; }
      else if (bo < 768){ src = fkb2; si = bo - 256; }
      else if (bo < 1024){ src = fvb1; si = bo - 768; }
      else if (bo < 1536){ src = fvb2; si = bo - 1024; }
      else if (bo < 1792){ src = kb; si = bo - 1536; }
      else if (bo < 2048){ src = vb; si = bo - 1792; }
      else { src = qb; si = bo - 2048; }
      bias[bo] = read_f(src, si, fbf);
    }
  }
}

// ---------------- fragment helpers (verified layouts) ----------------
__device__ __forceinline__ int swz_off(int row, int col){
  return row*256 + ((col & 248) ^ ((row & 7) << 3)) + (col & 7);
}
__device__ __forceinline__ short8 lda(const uint16_t* buf, int mt, int ks, int lane){
  int row = mt*16 + (lane & 15);
  int kc  = ks*4 + (lane >> 4);
  int off = row*256 + (((kc << 3) ^ ((row & 7) << 3)));
  return *(const short8*)(buf + off);
}
__device__ __forceinline__ short8 ldb(const uint16_t* W, int nt, int ks, int lane){
  return *(const short8*)(W + ((((nt << 3) + ks) << 6) + lane) * 8);
}
__device__ __forceinline__ f32x4 mfma16(short8 a, short8 b, f32x4 c){
  return __builtin_amdgcn_mfma_f32_16x16x32_bf16(a, b, c, 0, 0, 0);
}

// h_k = silu(E @ W1k + b1k) -> dstK ; h_v = silu(E @ W1v + b1v) -> dstV (one E pass)
__device__ __forceinline__ void gemm1_kv(const uint16_t* src,
                                         const uint16_t* W1k, const float* b1k, uint16_t* dstK,
                                         const uint16_t* W1v, const float* b1v, uint16_t* dstV,
                                         int lane, int nh){
  const int cl = lane & 15, kg = lane >> 4;
  f32x4 ak[2][4], av[2][4];
  #pragma unroll
  for (int i = 0; i < 4; i++){
    float bk = b1k[(nh*4 + i)*16 + cl];
    float bv = b1v[(nh*4 + i)*16 + cl];
    f32x4 ck = {bk,bk,bk,bk}, cv = {bv,bv,bv,bv};
    ak[0][i] = ck; ak[1][i] = ck;
    av[0][i] = cv; av[1][i] = cv;
  }
  #pragma unroll
  for (int ks = 0; ks < 8; ks++){
    short8 a0 = lda(src, 0, ks, lane);
    short8 a1 = lda(src, 1, ks, lane);
    #pragma unroll
    for (int i = 0; i < 4; i++){
      short8 bk = ldb(W1k, nh*4 + i, ks, lane);
      short8 bv = ldb(W1v, nh*4 + i, ks, lane);
      ak[0][i] = mfma16(a0, bk, ak[0][i]);
      ak[1][i] = mfma16(a1, bk, ak[1][i]);
      av[0][i] = mfma16(a0, bv, av[0][i]);
      av[1][i] = mfma16(a1, bv, av[1][i]);
    }
  }
  #pragma unroll
  for (int m = 0; m < 2; m++){
    int rowb = m*16 + kg*4;
    #pragma unroll
    for (int i = 0; i < 4; i++){
      int col = (nh*4 + i)*16 + cl;
      #pragma unroll
      for (int r = 0; r < 4; r++){
        float vk = ak[m][i][r];
        float vv = av[m][i][r];
        dstK[swz_off(rowb + r, col)] = f2bf(vk / (1.0f + __expf(-vk)));
        dstV[swz_off(rowb + r, col)] = f2bf(vv / (1.0f + __expf(-vv)));
      }
    }
  }
}

// gb = h @ W2 + b2 ; dst = gamma*xj + beta (xj in LDS, swizzled bf16)
__device__ __forceinline__ void gemm2_film(const uint16_t* src, const uint16_t* W2, const float* b2,
                                           const uint16_t* xj, uint16_t* dst, int lane, int nh){
  const int cl = lane & 15, kg = lane >> 4;
  #pragma unroll
  for (int ch = 0; ch < 2; ch++){
    f32x4 ag[2][2], ab[2][2];
    #pragma unroll
    for (int j = 0; j < 2; j++){
      int dt = nh*4 + ch*2 + j;
      float bg = b2[dt*16 + cl];
      float bb = b2[(16 + dt)*16 + cl];
      f32x4 cg = {bg,bg,bg,bg}, cb = {bb,bb,bb,bb};
      ag[0][j] = cg; ag[1][j] = cg; ab[0][j] = cb; ab[1][j] = cb;
    }
    #pragma unroll
    for (int ks = 0; ks < 8; ks++){
      short8 a0 = lda(src, 0, ks, lane);
      short8 a1 = lda(src, 1, ks, lane);
      #pragma unroll
      for (int j = 0; j < 2; j++){
        int dt = nh*4 + ch*2 + j;
        short8 bg = ldb(W2, dt, ks, lane);
        short8 bb = ldb(W2, 16 + dt, ks, lane);
        ag[0][j] = mfma16(a0, bg, ag[0][j]);
        ag[1][j] = mfma16(a1, bg, ag[1][j]);
        ab[0][j] = mfma16(a0, bb, ab[0][j]);
        ab[1][j] = mfma16(a1, bb, ab[1][j]);
      }
    }
    #pragma unroll
    for (int m = 0; m < 2; m++){
      int rowb = m*16 + kg*4;
      #pragma unroll
      for (int j = 0; j < 2; j++){
        int d = (nh*4 + ch*2 + j)*16 + cl;
        #pragma unroll
        for (int r = 0; r < 4; r++){
          int row = rowb + r;
          float x = bf2f(xj[swz_off(row, d)]);
          dst[swz_off(row, d)] = f2bf(ag[m][j][r] * x + ab[m][j][r]);
        }
      }
    }
  }
}

// K = kin @ k_proj + kb ; wave nh covers head nh; S[row][nh] = Q . K
__device__ __forceinline__ void gemm3_scores(const uint16_t* src, const uint16_t* W, const float* bs,
                                             const float* sQ, float (*sS)[4], int lane, int nh){
  const int cl = lane & 15, kg = lane >> 4;
  f32x4 acc[2][4];
  #pragma unroll
  for (int i = 0; i < 4; i++){
    float bb = bs[(nh*4 + i)*16 + cl];
    f32x4 c = {bb,bb,bb,bb};
    acc[0][i] = c; acc[1][i] = c;
  }
  #pragma unroll
  for (int ks = 0; ks < 8; ks++){
    short8 a0 = lda(src, 0, ks, lane);
    short8 a1 = lda(src, 1, ks, lane);
    #pragma unroll
    for (int i = 0; i < 4; i++){
      short8 bv = ldb(W, nh*4 + i, ks, lane);
      acc[0][i] = mfma16(a0, bv, acc[0][i]);
      acc[1][i] = mfma16(a1, bv, acc[1][i]);
    }
  }
  #pragma unroll
  for (int m = 0; m < 2; m++){
    int rowb = m*16 + kg*4;
    float p0=0.f, p1=0.f, p2=0.f, p3=0.f;
    #pragma unroll
    for (int i = 0; i < 4; i++){
      float qv = sQ[(nh*4 + i)*16 + cl];
      p0 += acc[m][i][0]*qv; p1 += acc[m][i][1]*qv;
      p2 += acc[m][i][2]*qv; p3 += acc[m][i][3]*qv;
    }
    float pr[4] = {p0, p1, p2, p3};
    #pragma unroll
    for (int r = 0; r < 4; r++){
      float v = pr[r];
      v += __shfl_xor(v, 1, 16);
      v += __shfl_xor(v, 2, 16);
      v += __shfl_xor(v, 4, 16);
      v += __shfl_xor(v, 8, 16);
      if (cl == 0) sS[rowb + r][nh] = v;
    }
  }
}

// V = vin @ v_proj + vb -> dst (swizzled bf16)
__device__ __forceinline__ void gemm3_store(const uint16_t* src, const uint16_t* W, const float* bs,
                                            uint16_t* dst, int lane, int nh){
  const int cl = lane & 15, kg = lane >> 4;
  f32x4 acc[2][4];
  #pragma unroll
  for (int i = 0; i < 4; i++){
    float bb = bs[(nh*4 + i)*16 + cl];
    f32x4 c = {bb,bb,bb,bb};
    acc[0][i] = c; acc[1][i] = c;
  }
  #pragma unroll
  for (int ks = 0; ks < 8; ks++){
    short8 a0 = lda(src, 0, ks, lane);
    short8 a1 = lda(src, 1, ks, lane);
    #pragma unroll
    for (int i = 0; i < 4; i++){
      short8 bv = ldb(W, nh*4 + i, ks, lane);
      acc[0][i] = mfma16(a0, bv, acc[0][i]);
      acc[1][i] = mfma16(a1, bv, acc[1][i]);
    }
  }
  #pragma unroll
  for (int m = 0; m < 2; m++){
    int rowb = m*16 + kg*4;
    #pragma unroll
    for (int i = 0; i < 4; i++){
      int col = (nh*4 + i)*16 + cl;
      #pragma unroll
      for (int r = 0; r < 4; r++)
        dst[swz_off(rowb + r, col)] = f2bf(acc[m][i][r]);
    }
  }
}

// ---------------- fused kernel: 1 block = 2 nodes (512 thr, 8 waves/CU) ----------------
__launch_bounds__(512, 1)
__global__ void fused_kernel(const void* nodes_i, const void* edges, const void* nodes_j, const void* maskp,
                             const void* wsv, float* out)
{
  const char* ws = (const char*)wsv;
  const int* flags = (const int*)ws;
  const int fbf = flags[0], mk = flags[1];
  const uint16_t* wu = (const uint16_t*)(ws + WU_OFF);
  const float* bias = (const float*)(ws + BIAS_OFF);
  const uint16_t* W1k = wu;
  const uint16_t* W1v = wu + 65536;
  const uint16_t* W2k = wu + 131072;
  const uint16_t* W2v = wu + 262144;
  const uint16_t* KBw = wu + 393216;
  const uint16_t* VBw = wu + 458752;
  const uint16_t* QBt = wu + 524288;
  const uint16_t* WoB = wu + 589824;
  const float* b1k = bias;
  const float* b2k = bias + 256;
  const float* b1v = bias + 768;
  const float* b2v = bias + 1024;
  const float* kbb = bias + 1536;
  const float* vbb = bias + 1792;
  const float* qbb = bias + 2048;

  __shared__ __align__(16) uint16_t bufE[2][KI*DM];   // E -> kin
  __shared__ __align__(16) uint16_t bufXJ[2][KI*DM];  // nodes_j (bf16, swizzled)
  __shared__ __align__(16) uint16_t bufA[2][KI*DM];   // h_k -> vin
  __shared__ __align__(16) uint16_t bufB[2][KI*DM];   // h_v -> V
  __shared__ float sQ[2][DM];
  __shared__ float sNI[2][DM];
  __shared__ float sS[2][KI][4];
  __shared__ float sP[2][KI][4];
  __shared__ float sO[2][DM];

  const int tid = threadIdx.x;
  const int g = tid >> 8;      // node half (0/1)
  const int th = tid & 255;    // thread within half
  const int lane = tid & 63;
  const int nh = (tid >> 6) & 3;   // N-quarter / head within half
  const int b = blockIdx.x;
  const int z = b >> 10;
  const int n = (b & 1023)*2 + g;
  const long ebase = ((long)(z*NNODE + n)) * (KI*DM);
  const long nbase = ((long)(z*NNODE + n)) * DM;

  // P0: stage nodes_i row + E + xj tiles (bf16, swizzled) — per half
  sNI[g][th] = read_f(nodes_i, nbase + th, fbf);
  if (fbf){
    const uint16_t* xp = (const uint16_t*)nodes_j;
    const uint16_t* ep = (const uint16_t*)edges;
    for (int c = th; c < 2048; c += 256){
      int sel = c >> 10, cc = c & 1023;
      int row = cc >> 5, kc = cc & 31;
      const uint16_t* src = sel ? ep : xp;
      uint16_t* dst = sel ? bufE[g] : bufXJ[g];
      short8 v = *(const short8*)(src + ebase + row*256 + kc*8);
      *(short8*)(dst + row*256 + (((kc << 3) ^ ((row & 7) << 3)))) = v;
    }
  } else {
    const float* xp = (const float*)nodes_j;
    const float* ep = (const float*)edges;
    for (int c = th; c < 2048; c += 256){
      int sel = c >> 10, cc = c & 1023;
      int row = cc >> 5, kc = cc & 31;
      const float* src = (sel ? ep : xp) + ebase + row*256 + kc*8;
      uint16_t* dst = sel ? bufE[g] : bufXJ[g];
      f32x4 x0 = *(const f32x4*)src;
      f32x4 x1 = *(const f32x4*)(src + 4);
      short8 v;
      v[0]=(short)f2bf(x0[0]); v[1]=(short)f2bf(x0[1]); v[2]=(short)f2bf(x0[2]); v[3]=(short)f2bf(x0[3]);
      v[4]=(short)f2bf(x1[0]); v[5]=(short)f2bf(x1[1]); v[6]=(short)f2bf(x1[2]); v[7]=(short)f2bf(x1[3]);
      *(short8*)(dst + row*256 + (((kc << 3) ^ ((row & 7) << 3)))) = v;
    }
  }
  __syncthreads();                               // B1

  // P1: Q projection (col = th, pre-scaled 1/8) + merged gemm1 (h_k, h_v)
  {
    const uint16_t* wrow = QBt + th*256;
    float a = qbb[th];
    for (int d = 0; d < 256; d += 8){
      short8 wv = *(const short8*)(wrow + d);
      #pragma unroll
      for (int j = 0; j < 8; j++)
        a += sNI[g][d + j] * bf2f((uint16_t)wv[j]);
    }
    sQ[g][th] = a * 0.125f;
  }
  gemm1_kv(bufE[g], W1k, b1k, bufA[g], W1v, b1v, bufB[g], lane, nh);
  __syncthreads();                               // B2  (E dead)

  // P2: gemm2 K: kin = gamma_k*xj + beta_k -> bufE
  gemm2_film(bufA[g], W2k, b2k, bufXJ[g], bufE[g], lane, nh);
  __syncthreads();                               // B3  (h_k dead)

  // P3: scores(kin) || gemm2 V: vin -> bufA
  gemm3_scores(bufE[g], KBw, kbb, sQ[g], sS[g], lane, nh);
  __builtin_amdgcn_sched_barrier(0);
  gemm2_film(bufB[g], W2v, b2v, bufXJ[g], bufA[g], lane, nh);
  __syncthreads();                               // B4  (h_v, xj dead)

  // P4: softmax (th 0-127) || V = vin @ VB -> bufB
  gemm3_store(bufA[g], VBw, vbb, bufB[g], lane, nh);
  if (th < 128){
    int h2 = th >> 5, k2 = th & 31;
    long mi = (long)(z*NNODE + n)*KI + k2;
    bool mval;
    if (mk == 0)      mval = ((const int*)maskp)[mi] != 0;
    else if (mk == 1) mval = ((const unsigned char*)maskp)[mi] != 0;
    else if (mk == 2) mval = ((const uint16_t*)maskp)[mi] != 0;
    else if (mk == 4) mval = ((const int*)maskp)[mi*2] != 0;
    else              mval = ((const float*)maskp)[mi] != 0.0f;
    unsigned long long bal = __ballot(mval);
    unsigned int gm = (unsigned int)(bal >> (tid & 32));
    bool anyT = (gm != 0u);
    float s = sS[g][k2][h2];
    if (anyT && !mval) s = -1e30f;
    float mx = s;
    mx = fmaxf(mx, __shfl_xor(mx, 16, 32));
    mx = fmaxf(mx, __shfl_xor(mx,  8, 32));
    mx = fmaxf(mx, __shfl_xor(mx,  4, 32));
    mx = fmaxf(mx, __shfl_xor(mx,  2, 32));
    mx = fmaxf(mx, __shfl_xor(mx,  1, 32));
    float e = __expf(s - mx);
    float su = e;
    su += __shfl_xor(su, 16, 32);
    su += __shfl_xor(su,  8, 32);
    su += __shfl_xor(su,  4, 32);
    su += __shfl_xor(su,  2, 32);
    su += __shfl_xor(su,  1, 32);
    sP[g][k2][h2] = e / su;
  }
  __syncthreads();                               // B5

  // P5: PV: col c = th; sO[e*4+h]
  {
    int h = th >> 6;
    float a = 0.0f;
    #pragma unroll 4
    for (int k = 0; k < KI; k++)
      a += sP[g][k][h] * bf2f(bufB[g][swz_off(k, th)]);
    sO[g][(th & 63)*4 + h] = a;
  }
  __syncthreads();                               // B6

  // P6: out projection: y[d=th] = sum_m sO[m] * Wo[d][m]
  {
    const uint16_t* wrow = WoB + th*256;
    float a = 0.0f;
    for (int m8 = 0; m8 < 256; m8 += 8){
      short8 wv = *(const short8*)(wrow + m8);
      #pragma unroll
      for (int j = 0; j < 8; j++)
        a += sO[g][m8 + j] * bf2f((uint16_t)wv[j]);
    }
    out[nbase + th] = a;
  }
}

extern "C" void kernel_launch(void* const* d_in, const int* in_sizes, int n_in,
                              void* d_out, int out_size, void* d_ws, size_t ws_size,
                              hipStream_t stream){
  // inputs: 0 nodes_i, 1 edges, 2 nodes_j, 3 nbr_mask, 4 fk_W1, 5 fk_b1,
  // 6 fk_W2, 7 fk_b2, 8 fv_W1, 9 fv_b1, 10 fv_W2, 11 fv_b2, 12 q_proj,
  // 13 k_proj, 14 v_proj, 15 q_bias, 16 k_bias, 17 v_bias, 18 out_W
  int* flags = (int*)d_ws;
  sniff_kernel<<<1, 256, 0, stream>>>((const uint32_t*)d_in[0], (const uint32_t*)d_in[3], flags);
  prep_kernel<<<1024, 256, 0, stream>>>(d_in[4], d_in[5], d_in[6], d_in[7],
                                        d_in[8], d_in[9], d_in[10], d_in[11],
                                        d_in[12], d_in[13], d_in[14],
                                        d_in[15], d_in[16], d_in[17],
                                        d_in[18], d_ws);
  fused_kernel<<<NNODE, 512, 0, stream>>>(d_in[0], d_in[1], d_in[2], d_in[3], d_ws, (float*)d_out);
}

// Round 19
// 635.646 us; speedup vs baseline: 1.0440x; 1.0003x over previous
//
#include <hip/hip_runtime.h>
#include <stdint.h>

#define NNODE 2048
#define KI 32
#define DM 256

using short8 = __attribute__((ext_vector_type(8))) short;
using f32x4  = __attribute__((ext_vector_type(4))) float;

// ---- ws layout (bytes) ----
#define WU_OFF   1024            // u16 weights, 655360 elems
#define BIAS_OFF 1312768         // f32 bias, 2304

__device__ __forceinline__ float bf2f(uint16_t u){
  union { uint32_t i; float f; } v; v.i = ((uint32_t)u) << 16; return v.f;
}
__device__ __forceinline__ uint16_t f2bf(float f){
  union { float f; uint32_t i; } v; v.f = f;
  uint32_t x = v.i;
  return (uint16_t)((x + 0x7FFFu + ((x >> 16) & 1u)) >> 16);
}
__device__ __forceinline__ float read_f(const void* p, long idx, int fbf){
  return fbf ? bf2f(((const uint16_t*)p)[idx]) : ((const float*)p)[idx];
}

// ---------------- sniff -> ws flags ----------------
__global__ void sniff_kernel(const uint32_t* ni, const uint32_t* mask, int* flags){
  __shared__ int cnt[6];
  int t = threadIdx.x;
  if (t < 6) cnt[t] = 0;
  __syncthreads();
  {
    uint32_t u = ni[t];
    uint32_t lo = u & 0xFFFFu;
    uint32_t exl = (lo >> 7) & 0xFFu;
    if ((lo & 0x7FFFu) == 0u || (exl >= 100u && exl <= 140u)) atomicAdd(&cnt[0], 1);
  }
  if (t < 64){
    uint32_t u = mask[t];
    if (!(u == 0u || u == 1u)) atomicAdd(&cnt[1], 1);
    if (!(u == 0u || u == 0x3F800000u)) atomicAdd(&cnt[2], 1);
    uint32_t lo = u & 0xFFFFu, hi = u >> 16;
    if (!((lo == 0u || lo == 0x3F80u) && (hi == 0u || hi == 0x3F80u))) atomicAdd(&cnt[3], 1);
    if ((t & 1) && u != 0u) atomicAdd(&cnt[4], 1);
    if (!(t & 1) && u == 1u) atomicAdd(&cnt[5], 1);
  }
  __syncthreads();
  if (t == 0){
    flags[0] = (cnt[0] >= 160) ? 1 : 0;   // 1 = bf16 storage, 0 = f32
    int mk;
    if (cnt[1] == 0) mk = (cnt[4] == 0 && cnt[5] > 0) ? 4 : 0;
    else if (cnt[2] == 0) mk = 3;
    else if (cnt[3] == 0) mk = 2;
    else mk = 1;
    flags[1] = mk;
  }
}

// ---------------- prep: weights -> MFMA-fragment-ordered bf16 in ws ----------------
__global__ void prep_kernel(const void* fkW1, const void* fkb1, const void* fkW2, const void* fkb2,
                            const void* fvW1, const void* fvb1, const void* fvW2, const void* fvb2,
                            const void* qW, const void* kW, const void* vW,
                            const void* qb, const void* kb, const void* vb,
                            const void* oW, void* wsv){
  char* ws = (char*)wsv;
  const int fbf = ((const int*)ws)[0];
  uint16_t* wu = (uint16_t*)(ws + WU_OFF);
  float* bias = (float*)(ws + BIAS_OFF);
  const int total = 655360 + 2304;
  for (int o = blockIdx.x*blockDim.x + threadIdx.x; o < total; o += gridDim.x*blockDim.x){
    if (o < 655360){
      const void* src; long si;
      if (o < 131072){
        int t = o & 65535;
        src = (o < 65536) ? fkW1 : fvW1;
        int j = t & 7, l = (t >> 3) & 63, ks = (t >> 9) & 7, nt = t >> 12;
        int n = nt*16 + (l & 15);
        int k = ks*32 + ((l >> 4) << 3) + j;
        si = (long)k*256 + n;
      } else if (o < 393216){
        int oo = o - 131072;
        int t = oo & 131071;
        src = (oo < 131072) ? fkW2 : fvW2;
        int j = t & 7, l = (t >> 3) & 63, ks = (t >> 9) & 7, nt = t >> 12;
        int n = nt*16 + (l & 15);
        int k = ks*32 + ((l >> 4) << 3) + j;
        si = (long)k*512 + n;
      } else if (o < 524288){
        int oo = o - 393216;
        int t = oo & 65535;
        src = (oo < 65536) ? kW : vW;
        int j = t & 7, l = (t >> 3) & 63, ks = (t >> 9) & 7, nt = t >> 12;
        int n = nt*16 + (l & 15);       // n = h*64+e
        int k = ks*32 + ((l >> 4) << 3) + j;
        si = (long)(n >> 6)*16384 + (long)k*64 + (n & 63);
      } else if (o < 589824){
        int t = o - 524288;
        int col = t >> 8, d = t & 255;
        src = qW;
        si = (long)(col >> 6)*16384 + (long)d*64 + (col & 63);
      } else {
        int t = o - 589824;
        src = oW;
        si = t;
      }
      wu[o] = f2bf(read_f(src, si, fbf));
    } else {
      int bo = o - 655360;
      const void* src; long si;
      if (bo < 256){ src = fkb1; si = bo; }
      else if (bo < 768){ src = fkb2; si = bo - 256; }
      else if (bo < 1024){ src = fvb1; si = bo - 768; }
      else if (bo < 1536){ src = fvb2; si = bo - 1024; }
      else if (bo < 1792){ src = kb; si = bo - 1536; }
      else if (bo < 2048){ src = vb; si = bo - 1792; }
      else { src = qb; si = bo - 2048; }
      bias[bo] = read_f(src, si, fbf);
    }
  }
}

// ---------------- fragment helpers (verified layouts) ----------------
__device__ __forceinline__ int swz_off(int row, int col){
  return row*256 + ((col & 248) ^ ((row & 7) << 3)) + (col & 7);
}
__device__ __forceinline__ short8 lda(const uint16_t* buf, int mt, int ks, int lane){
  int row = mt*16 + (lane & 15);
  int kc  = ks*4 + (lane >> 4);
  int off = row*256 + (((kc << 3) ^ ((row & 7) << 3)));
  return *(const short8*)(buf + off);
}
__device__ __forceinline__ short8 ldb(const uint16_t* W, int nt, int ks, int lane){
  return *(const short8*)(W + ((((nt << 3) + ks) << 6) + lane) * 8);
}
__device__ __forceinline__ f32x4 mfma16(short8 a, short8 b, f32x4 c){
  return __builtin_amdgcn_mfma_f32_16x16x32_bf16(a, b, c, 0, 0, 0);
}

// h_k = silu(E @ W1k + b1k) -> dstK ; h_v = silu(E @ W1v + b1v) -> dstV (one E pass)
__device__ __forceinline__ void gemm1_kv(const uint16_t* src,
                                         const uint16_t* W1k, const float* b1k, uint16_t* dstK,
                                         const uint16_t* W1v, const float* b1v, uint16_t* dstV,
                                         int lane, int nh){
  const int cl = lane & 15, kg = lane >> 4;
  f32x4 ak[2][4], av[2][4];
  #pragma unroll
  for (int i = 0; i < 4; i++){
    float bk = b1k[(nh*4 + i)*16 + cl];
    float bv = b1v[(nh*4 + i)*16 + cl];
    f32x4 ck = {bk,bk,bk,bk}, cv = {bv,bv,bv,bv};
    ak[0][i] = ck; ak[1][i] = ck;
    av[0][i] = cv; av[1][i] = cv;
  }
  #pragma unroll
  for (int ks = 0; ks < 8; ks++){
    short8 a0 = lda(src, 0, ks, lane);
    short8 a1 = lda(src, 1, ks, lane);
    #pragma unroll
    for (int i = 0; i < 4; i++){
      short8 bk = ldb(W1k, nh*4 + i, ks, lane);
      short8 bv = ldb(W1v, nh*4 + i, ks, lane);
      ak[0][i] = mfma16(a0, bk, ak[0][i]);
      ak[1][i] = mfma16(a1, bk, ak[1][i]);
      av[0][i] = mfma16(a0, bv, av[0][i]);
      av[1][i] = mfma16(a1, bv, av[1][i]);
    }
  }
  #pragma unroll
  for (int m = 0; m < 2; m++){
    int rowb = m*16 + kg*4;
    #pragma unroll
    for (int i = 0; i < 4; i++){
      int col = (nh*4 + i)*16 + cl;
      #pragma unroll
      for (int r = 0; r < 4; r++){
        float vk = ak[m][i][r];
        float vv = av[m][i][r];
        dstK[swz_off(rowb + r, col)] = f2bf(vk / (1.0f + __expf(-vk)));
        dstV[swz_off(rowb + r, col)] = f2bf(vv / (1.0f + __expf(-vv)));
      }
    }
  }
}

// gb = h @ W2 + b2 ; dst = gamma*xj + beta (xj in LDS, swizzled bf16)
__device__ __forceinline__ void gemm2_film(const uint16_t* src, const uint16_t* W2, const float* b2,
                                           const uint16_t* xj, uint16_t* dst, int lane, int nh){
  const int cl = lane & 15, kg = lane >> 4;
  #pragma unroll
  for (int ch = 0; ch < 2; ch++){
    f32x4 ag[2][2], ab[2][2];
    #pragma unroll
    for (int j = 0; j < 2; j++){
      int dt = nh*4 + ch*2 + j;
      float bg = b2[dt*16 + cl];
      float bb = b2[(16 + dt)*16 + cl];
      f32x4 cg = {bg,bg,bg,bg}, cb = {bb,bb,bb,bb};
      ag[0][j] = cg; ag[1][j] = cg; ab[0][j] = cb; ab[1][j] = cb;
    }
    #pragma unroll
    for (int ks = 0; ks < 8; ks++){
      short8 a0 = lda(src, 0, ks, lane);
      short8 a1 = lda(src, 1, ks, lane);
      #pragma unroll
      for (int j = 0; j < 2; j++){
        int dt = nh*4 + ch*2 + j;
        short8 bg = ldb(W2, dt, ks, lane);
        short8 bb = ldb(W2, 16 + dt, ks, lane);
        ag[0][j] = mfma16(a0, bg, ag[0][j]);
        ag[1][j] = mfma16(a1, bg, ag[1][j]);
        ab[0][j] = mfma16(a0, bb, ab[0][j]);
        ab[1][j] = mfma16(a1, bb, ab[1][j]);
      }
    }
    #pragma unroll
    for (int m = 0; m < 2; m++){
      int rowb = m*16 + kg*4;
      #pragma unroll
      for (int j = 0; j < 2; j++){
        int d = (nh*4 + ch*2 + j)*16 + cl;
        #pragma unroll
        for (int r = 0; r < 4; r++){
          int row = rowb + r;
          float x = bf2f(xj[swz_off(row, d)]);
          dst[swz_off(row, d)] = f2bf(ag[m][j][r] * x + ab[m][j][r]);
        }
      }
    }
  }
}

// K = kin @ k_proj + kb ; wave nh covers head nh; S[row][nh] = Q . K
__device__ __forceinline__ void gemm3_scores(const uint16_t* src, const uint16_t* W, const float* bs,
                                             const float* sQ, float (*sS)[4], int lane, int nh){
  const int cl = lane & 15, kg = lane >> 4;
  f32x4 acc[2][4];
  #pragma unroll
  for (int i = 0; i < 4; i++){
    float bb = bs[(nh*4 + i)*16 + cl];
    f32x4 c = {bb,bb,bb,bb};
    acc[0][i] = c; acc[1][i] = c;
  }
  #pragma unroll
  for (int ks = 0; ks < 8; ks++){
    short8 a0 = lda(src, 0, ks, lane);
    short8 a1 = lda(src, 1, ks, lane);
    #pragma unroll
    for (int i = 0; i < 4; i++){
      short8 bv = ldb(W, nh*4 + i, ks, lane);
      acc[0][i] = mfma16(a0, bv, acc[0][i]);
      acc[1][i] = mfma16(a1, bv, acc[1][i]);
    }
  }
  #pragma unroll
  for (int m = 0; m < 2; m++){
    int rowb = m*16 + kg*4;
    float p0=0.f, p1=0.f, p2=0.f, p3=0.f;
    #pragma unroll
    for (int i = 0; i < 4; i++){
      float qv = sQ[(nh*4 + i)*16 + cl];
      p0 += acc[m][i][0]*qv; p1 += acc[m][i][1]*qv;
      p2 += acc[m][i][2]*qv; p3 += acc[m][i][3]*qv;
    }
    float pr[4] = {p0, p1, p2, p3};
    #pragma unroll
    for (int r = 0; r < 4; r++){
      float v = pr[r];
      v += __shfl_xor(v, 1, 16);
      v += __shfl_xor(v, 2, 16);
      v += __shfl_xor(v, 4, 16);
      v += __shfl_xor(v, 8, 16);
      if (cl == 0) sS[rowb + r][nh] = v;
    }
  }
}

// V = vin @ v_proj + vb -> dst (swizzled bf16)
__device__ __forceinline__ void gemm3_store(const uint16_t* src, const uint16_t* W, const float* bs,
                                            uint16_t* dst, int lane, int nh){
  const int cl = lane & 15, kg = lane >> 4;
  f32x4 acc[2][4];
  #pragma unroll
  for (int i = 0; i < 4; i++){
    float bb = bs[(nh*4 + i)*16 + cl];
    f32x4 c = {bb,bb,bb,bb};
    acc[0][i] = c; acc[1][i] = c;
  }
  #pragma unroll
  for (int ks = 0; ks < 8; ks++){
    short8 a0 = lda(src, 0, ks, lane);
    short8 a1 = lda(src, 1, ks, lane);
    #pragma unroll
    for (int i = 0; i < 4; i++){
      short8 bv = ldb(W, nh*4 + i, ks, lane);
      acc[0][i] = mfma16(a0, bv, acc[0][i]);
      acc[1][i] = mfma16(a1, bv, acc[1][i]);
    }
  }
  #pragma unroll
  for (int m = 0; m < 2; m++){
    int rowb = m*16 + kg*4;
    #pragma unroll
    for (int i = 0; i < 4; i++){
      int col = (nh*4 + i)*16 + cl;
      #pragma unroll
      for (int r = 0; r < 4; r++)
        dst[swz_off(rowb + r, col)] = f2bf(acc[m][i][r]);
    }
  }
}

// ---------------- fused kernel: 1 block = 2 nodes (512 thr, 2 waves/SIMD, 256-VGPR budget) ----------------
__launch_bounds__(512, 2)
__global__ void fused_kernel(const void* nodes_i, const void* edges, const void* nodes_j, const void* maskp,
                             const void* wsv, float* out)
{
  const char* ws = (const char*)wsv;
  const int* flags = (const int*)ws;
  const int fbf = flags[0], mk = flags[1];
  const uint16_t* wu = (const uint16_t*)(ws + WU_OFF);
  const float* bias = (const float*)(ws + BIAS_OFF);
  const uint16_t* W1k = wu;
  const uint16_t* W1v = wu + 65536;
  const uint16_t* W2k = wu + 131072;
  const uint16_t* W2v = wu + 262144;
  const uint16_t* KBw = wu + 393216;
  const uint16_t* VBw = wu + 458752;
  const uint16_t* QBt = wu + 524288;
  const uint16_t* WoB = wu + 589824;
  const float* b1k = bias;
  const float* b2k = bias + 256;
  const float* b1v = bias + 768;
  const float* b2v = bias + 1024;
  const float* kbb = bias + 1536;
  const float* vbb = bias + 1792;
  const float* qbb = bias + 2048;

  __shared__ __align__(16) uint16_t bufE[2][KI*DM];   // E -> kin
  __shared__ __align__(16) uint16_t bufXJ[2][KI*DM];  // nodes_j (bf16, swizzled)
  __shared__ __align__(16) uint16_t bufA[2][KI*DM];   // h_k -> vin
  __shared__ __align__(16) uint16_t bufB[2][KI*DM];   // h_v -> V
  __shared__ float sQ[2][DM];
  __shared__ float sNI[2][DM];
  __shared__ float sS[2][KI][4];
  __shared__ float sP[2][KI][4];
  __shared__ float sO[2][DM];

  const int tid = threadIdx.x;
  const int g = tid >> 8;      // node half (0/1)
  const int th = tid & 255;    // thread within half
  const int lane = tid & 63;
  const int nh = (tid >> 6) & 3;   // N-quarter / head within half
  const int b = blockIdx.x;
  const int z = b >> 10;
  const int n = (b & 1023)*2 + g;
  const long ebase = ((long)(z*NNODE + n)) * (KI*DM);
  const long nbase = ((long)(z*NNODE + n)) * DM;

  // P0: stage nodes_i row + E + xj tiles (bf16, swizzled) — per half
  sNI[g][th] = read_f(nodes_i, nbase + th, fbf);
  if (fbf){
    const uint16_t* xp = (const uint16_t*)nodes_j;
    const uint16_t* ep = (const uint16_t*)edges;
    for (int c = th; c < 2048; c += 256){
      int sel = c >> 10, cc = c & 1023;
      int row = cc >> 5, kc = cc & 31;
      const uint16_t* src = sel ? ep : xp;
      uint16_t* dst = sel ? bufE[g] : bufXJ[g];
      short8 v = *(const short8*)(src + ebase + row*256 + kc*8);
      *(short8*)(dst + row*256 + (((kc << 3) ^ ((row & 7) << 3)))) = v;
    }
  } else {
    const float* xp = (const float*)nodes_j;
    const float* ep = (const float*)edges;
    for (int c = th; c < 2048; c += 256){
      int sel = c >> 10, cc = c & 1023;
      int row = cc >> 5, kc = cc & 31;
      const float* src = (sel ? ep : xp) + ebase + row*256 + kc*8;
      uint16_t* dst = sel ? bufE[g] : bufXJ[g];
      f32x4 x0 = *(const f32x4*)src;
      f32x4 x1 = *(const f32x4*)(src + 4);
      short8 v;
      v[0]=(short)f2bf(x0[0]); v[1]=(short)f2bf(x0[1]); v[2]=(short)f2bf(x0[2]); v[3]=(short)f2bf(x0[3]);
      v[4]=(short)f2bf(x1[0]); v[5]=(short)f2bf(x1[1]); v[6]=(short)f2bf(x1[2]); v[7]=(short)f2bf(x1[3]);
      *(short8*)(dst + row*256 + (((kc << 3) ^ ((row & 7) << 3)))) = v;
    }
  }
  __syncthreads();                               // B1

  // P1: Q projection (col = th, pre-scaled 1/8) + merged gemm1 (h_k, h_v)
  {
    const uint16_t* wrow = QBt + th*256;
    float a = qbb[th];
    for (int d = 0; d < 256; d += 8){
      short8 wv = *(const short8*)(wrow + d);
      #pragma unroll
      for (int j = 0; j < 8; j++)
        a += sNI[g][d + j] * bf2f((uint16_t)wv[j]);
    }
    sQ[g][th] = a * 0.125f;
  }
  gemm1_kv(bufE[g], W1k, b1k, bufA[g], W1v, b1v, bufB[g], lane, nh);
  __syncthreads();                               // B2  (E dead)

  // P2: gemm2 K: kin = gamma_k*xj + beta_k -> bufE
  gemm2_film(bufA[g], W2k, b2k, bufXJ[g], bufE[g], lane, nh);
  __syncthreads();                               // B3  (h_k dead)

  // P3: scores(kin) || gemm2 V: vin -> bufA
  gemm3_scores(bufE[g], KBw, kbb, sQ[g], sS[g], lane, nh);
  __builtin_amdgcn_sched_barrier(0);
  gemm2_film(bufB[g], W2v, b2v, bufXJ[g], bufA[g], lane, nh);
  __syncthreads();                               // B4  (h_v, xj dead)

  // P4: softmax (th 0-127) || V = vin @ VB -> bufB
  gemm3_store(bufA[g], VBw, vbb, bufB[g], lane, nh);
  if (th < 128){
    int h2 = th >> 5, k2 = th & 31;
    long mi = (long)(z*NNODE + n)*KI + k2;
    bool mval;
    if (mk == 0)      mval = ((const int*)maskp)[mi] != 0;
    else if (mk == 1) mval = ((const unsigned char*)maskp)[mi] != 0;
    else if (mk == 2) mval = ((const uint16_t*)maskp)[mi] != 0;
    else if (mk == 4) mval = ((const int*)maskp)[mi*2] != 0;
    else              mval = ((const float*)maskp)[mi] != 0.0f;
    unsigned long long bal = __ballot(mval);
    unsigned int gm = (unsigned int)(bal >> (tid & 32));
    bool anyT = (gm != 0u);
    float s = sS[g][k2][h2];
    if (anyT && !mval) s = -1e30f;
    float mx = s;
    mx = fmaxf(mx, __shfl_xor(mx, 16, 32));
    mx = fmaxf(mx, __shfl_xor(mx,  8, 32));
    mx = fmaxf(mx, __shfl_xor(mx,  4, 32));
    mx = fmaxf(mx, __shfl_xor(mx,  2, 32));
    mx = fmaxf(mx, __shfl_xor(mx,  1, 32));
    float e = __expf(s - mx);
    float su = e;
    su += __shfl_xor(su, 16, 32);
    su += __shfl_xor(su,  8, 32);
    su += __shfl_xor(su,  4, 32);
    su += __shfl_xor(su,  2, 32);
    su += __shfl_xor(su,  1, 32);
    sP[g][k2][h2] = e / su;
  }
  __syncthreads();                               // B5

  // P5: PV: col c = th; sO[e*4+h]
  {
    int h = th >> 6;
    float a = 0.0f;
    #pragma unroll 4
    for (int k = 0; k < KI; k++)
      a += sP[g][k][h] * bf2f(bufB[g][swz_off(k, th)]);
    sO[g][(th & 63)*4 + h] = a;
  }
  __syncthreads();                               // B6

  // P6: out projection: y[d=th] = sum_m sO[m] * Wo[d][m]
  {
    const uint16_t* wrow = WoB + th*256;
    float a = 0.0f;
    for (int m8 = 0; m8 < 256; m8 += 8){
      short8 wv = *(const short8*)(wrow + m8);
      #pragma unroll
      for (int j = 0; j < 8; j++)
        a += sO[g][m8 + j] * bf2f((uint16_t)wv[j]);
    }
    out[nbase + th] = a;
  }
}

extern "C" void kernel_launch(void* const* d_in, const int* in_sizes, int n_in,
                              void* d_out, int out_size, void* d_ws, size_t ws_size,
                              hipStream_t stream){
  // inputs: 0 nodes_i, 1 edges, 2 nodes_j, 3 nbr_mask, 4 fk_W1, 5 fk_b1,
  // 6 fk_W2, 7 fk_b2, 8 fv_W1, 9 fv_b1, 10 fv_W2, 11 fv_b2, 12 q_proj,
  // 13 k_proj, 14 v_proj, 15 q_bias, 16 k_bias, 17 v_bias, 18 out_W
  int* flags = (int*)d_ws;
  sniff_kernel<<<1, 256, 0, stream>>>((const uint32_t*)d_in[0], (const uint32_t*)d_in[3], flags);
  prep_kernel<<<1024, 256, 0, stream>>>(d_in[4], d_in[5], d_in[6], d_in[7],
                                        d_in[8], d_in[9], d_in[10], d_in[11],
                                        d_in[12], d_in[13], d_in[14],
                                        d_in[15], d_in[16], d_in[17],
                                        d_in[18], d_ws);
  fused_kernel<<<NNODE, 512, 0, stream>>>(d_in[0], d_in[1], d_in[2], d_in[3], d_ws, (float*)d_out);
}

// Round 20
// 469.193 us; speedup vs baseline: 1.4144x; 1.3548x over previous
//
#include <hip/hip_runtime.h>
#include <stdint.h>

#define NNODE 2048
#define KI 32
#define DM 256

using short8 = __attribute__((ext_vector_type(8))) short;
using f32x4  = __attribute__((ext_vector_type(4))) float;

// ---- ws layout (bytes) ----
#define WU_OFF   1024            // u16 weights, 655360 elems
#define BIAS_OFF 1312768         // f32 bias, 2304

__device__ __forceinline__ float bf2f(uint16_t u){
  union { uint32_t i; float f; } v; v.i = ((uint32_t)u) << 16; return v.f;
}
__device__ __forceinline__ uint16_t f2bf(float f){
  union { float f; uint32_t i; } v; v.f = f;
  uint32_t x = v.i;
  return (uint16_t)((x + 0x7FFFu + ((x >> 16) & 1u)) >> 16);
}
__device__ __forceinline__ float read_f(const void* p, long idx, int fbf){
  return fbf ? bf2f(((const uint16_t*)p)[idx]) : ((const float*)p)[idx];
}

// ---------------- sniff -> ws flags ----------------
__global__ void sniff_kernel(const uint32_t* ni, const uint32_t* mask, int* flags){
  __shared__ int cnt[6];
  int t = threadIdx.x;
  if (t < 6) cnt[t] = 0;
  __syncthreads();
  {
    uint32_t u = ni[t];
    uint32_t lo = u & 0xFFFFu;
    uint32_t exl = (lo >> 7) & 0xFFu;
    if ((lo & 0x7FFFu) == 0u || (exl >= 100u && exl <= 140u)) atomicAdd(&cnt[0], 1);
  }
  if (t < 64){
    uint32_t u = mask[t];
    if (!(u == 0u || u == 1u)) atomicAdd(&cnt[1], 1);
    if (!(u == 0u || u == 0x3F800000u)) atomicAdd(&cnt[2], 1);
    uint32_t lo = u & 0xFFFFu, hi = u >> 16;
    if (!((lo == 0u || lo == 0x3F80u) && (hi == 0u || hi == 0x3F80u))) atomicAdd(&cnt[3], 1);
    if ((t & 1) && u != 0u) atomicAdd(&cnt[4], 1);
    if (!(t & 1) && u == 1u) atomicAdd(&cnt[5], 1);
  }
  __syncthreads();
  if (t == 0){
    flags[0] = (cnt[0] >= 160) ? 1 : 0;   // 1 = bf16 storage, 0 = f32
    int mk;
    if (cnt[1] == 0) mk = (cnt[4] == 0 && cnt[5] > 0) ? 4 : 0;
    else if (cnt[2] == 0) mk = 3;
    else if (cnt[3] == 0) mk = 2;
    else mk = 1;
    flags[1] = mk;
  }
}

// ---------------- prep: weights -> MFMA-fragment-ordered bf16 in ws ----------------
__global__ void prep_kernel(const void* fkW1, const void* fkb1, const void* fkW2, const void* fkb2,
                            const void* fvW1, const void* fvb1, const void* fvW2, const void* fvb2,
                            const void* qW, const void* kW, const void* vW,
                            const void* qb, const void* kb, const void* vb,
                            const void* oW, void* wsv){
  char* ws = (char*)wsv;
  const int fbf = ((const int*)ws)[0];
  uint16_t* wu = (uint16_t*)(ws + WU_OFF);
  float* bias = (float*)(ws + BIAS_OFF);
  const int total = 655360 + 2304;
  for (int o = blockIdx.x*blockDim.x + threadIdx.x; o < total; o += gridDim.x*blockDim.x){
    if (o < 655360){
      const void* src; long si;
      if (o < 131072){
        int t = o & 65535;
        src = (o < 65536) ? fkW1 : fvW1;
        int j = t & 7, l = (t >> 3) & 63, ks = (t >> 9) & 7, nt = t >> 12;
        int n = nt*16 + (l & 15);
        int k = ks*32 + ((l >> 4) << 3) + j;
        si = (long)k*256 + n;
      } else if (o < 393216){
        int oo = o - 131072;
        int t = oo & 131071;
        src = (oo < 131072) ? fkW2 : fvW2;
        int j = t & 7, l = (t >> 3) & 63, ks = (t >> 9) & 7, nt = t >> 12;
        int n = nt*16 + (l & 15);
        int k = ks*32 + ((l >> 4) << 3) + j;
        si = (long)k*512 + n;
      } else if (o < 524288){
        int oo = o - 393216;
        int t = oo & 65535;
        src = (oo < 65536) ? kW : vW;
        int j = t & 7, l = (t >> 3) & 63, ks = (t >> 9) & 7, nt = t >> 12;
        int n = nt*16 + (l & 15);       // n = h*64+e
        int k = ks*32 + ((l >> 4) << 3) + j;
        si = (long)(n >> 6)*16384 + (long)k*64 + (n & 63);
      } else if (o < 589824){
        int t = o - 524288;
        int col = t >> 8, d = t & 255;
        src = qW;
        si = (long)(col >> 6)*16384 + (long)d*64 + (col & 63);
      } else {
        int t = o - 589824;
        src = oW;
        si = t;
      }
      wu[o] = f2bf(read_f(src, si, fbf));
    } else {
      int bo = o - 655360;
      const void* src; long si;
      if (bo < 256){ src = fkb1; si = bo; }
      else if (bo < 768){ src = fkb2; si = bo - 256; }
      else if (bo < 1024){ src = fvb1; si = bo - 768; }
      else if (bo < 1536){ src = fvb2; si = bo - 1024; }
      else if (bo < 1792){ src = kb; si = bo - 1536; }
      else if (bo < 2048){ src = vb; si = bo - 1792; }
      else { src = qb; si = bo - 2048; }
      bias[bo] = read_f(src, si, fbf);
    }
  }
}

// ---------------- fragment helpers (verified layouts) ----------------
__device__ __forceinline__ int swz_off(int row, int col){
  return row*256 + ((col & 248) ^ ((row & 7) << 3)) + (col & 7);
}
__device__ __forceinline__ short8 lda(const uint16_t* buf, int mt, int ks, int lane){
  int row = mt*16 + (lane & 15);
  int kc  = ks*4 + (lane >> 4);
  int off = row*256 + (((kc << 3) ^ ((row & 7) << 3)));
  return *(const short8*)(buf + off);
}
__device__ __forceinline__ short8 ldb(const uint16_t* W, int nt, int ks, int lane){
  return *(const short8*)(W + ((((nt << 3) + ks) << 6) + lane) * 8);
}
__device__ __forceinline__ f32x4 mfma16(short8 a, short8 b, f32x4 c){
  return __builtin_amdgcn_mfma_f32_16x16x32_bf16(a, b, c, 0, 0, 0);
}

// h = silu(src @ W1 + b1) -> dst ; CHUNKED: 2 passes of 2 n-tiles (<=16 acc regs live)
__device__ __forceinline__ void gemm1_silu(const uint16_t* src, const uint16_t* W1, const float* b1,
                                           uint16_t* dst, int lane, int nh){
  const int cl = lane & 15, kg = lane >> 4;
  #pragma unroll
  for (int ic = 0; ic < 2; ic++){
    f32x4 acc[2][2];
    #pragma unroll
    for (int i = 0; i < 2; i++){
      float bb = b1[(nh*4 + ic*2 + i)*16 + cl];
      f32x4 c = {bb,bb,bb,bb};
      acc[0][i] = c; acc[1][i] = c;
    }
    #pragma unroll
    for (int ks = 0; ks < 8; ks++){
      short8 a0 = lda(src, 0, ks, lane);
      short8 a1 = lda(src, 1, ks, lane);
      #pragma unroll
      for (int i = 0; i < 2; i++){
        short8 bv = ldb(W1, nh*4 + ic*2 + i, ks, lane);
        acc[0][i] = mfma16(a0, bv, acc[0][i]);
        acc[1][i] = mfma16(a1, bv, acc[1][i]);
      }
    }
    #pragma unroll
    for (int m = 0; m < 2; m++){
      int rowb = m*16 + kg*4;
      #pragma unroll
      for (int i = 0; i < 2; i++){
        int col = (nh*4 + ic*2 + i)*16 + cl;
        #pragma unroll
        for (int r = 0; r < 4; r++){
          float v = acc[m][i][r];
          dst[swz_off(rowb + r, col)] = f2bf(v / (1.0f + __expf(-v)));
        }
      }
    }
    __builtin_amdgcn_sched_barrier(0);
  }
}

// gb = h @ W2 + b2 ; dst = gamma*xj + beta ; CHUNKED: 4 passes of 1 dt ({gamma,beta} pair)
__device__ __forceinline__ void gemm2_film(const uint16_t* src, const uint16_t* W2, const float* b2,
                                           const uint16_t* xj, uint16_t* dst, int lane, int nh){
  const int cl = lane & 15, kg = lane >> 4;
  #pragma unroll
  for (int ch = 0; ch < 4; ch++){
    int dt = nh*4 + ch;
    float bg = b2[dt*16 + cl];
    float bb = b2[(16 + dt)*16 + cl];
    f32x4 ag0 = {bg,bg,bg,bg}, ag1 = ag0;
    f32x4 ab0 = {bb,bb,bb,bb}, ab1 = ab0;
    #pragma unroll
    for (int ks = 0; ks < 8; ks++){
      short8 a0 = lda(src, 0, ks, lane);
      short8 a1 = lda(src, 1, ks, lane);
      short8 wg = ldb(W2, dt, ks, lane);
      short8 wb = ldb(W2, 16 + dt, ks, lane);
      ag0 = mfma16(a0, wg, ag0);
      ag1 = mfma16(a1, wg, ag1);
      ab0 = mfma16(a0, wb, ab0);
      ab1 = mfma16(a1, wb, ab1);
    }
    int d = dt*16 + cl;
    #pragma unroll
    for (int m = 0; m < 2; m++){
      int rowb = m*16 + kg*4;
      #pragma unroll
      for (int r = 0; r < 4; r++){
        int row = rowb + r;
        float g = (m == 0) ? ag0[r] : ag1[r];
        float be = (m == 0) ? ab0[r] : ab1[r];
        float x = bf2f(xj[swz_off(row, d)]);
        dst[swz_off(row, d)] = f2bf(g * x + be);
      }
    }
    __builtin_amdgcn_sched_barrier(0);
  }
}

// K = kin @ k_proj + kb ; CHUNKED 2x ; S[row][nh] = Q . K folded via persistent p[2][4]
__device__ __forceinline__ void gemm3_scores(const uint16_t* src, const uint16_t* W, const float* bs,
                                             const float* sQ, float (*sS)[4], int lane, int nh){
  const int cl = lane & 15, kg = lane >> 4;
  float p[2][4] = {{0.f,0.f,0.f,0.f},{0.f,0.f,0.f,0.f}};
  #pragma unroll
  for (int ic = 0; ic < 2; ic++){
    f32x4 acc[2][2];
    #pragma unroll
    for (int i = 0; i < 2; i++){
      float bb = bs[(nh*4 + ic*2 + i)*16 + cl];
      f32x4 c = {bb,bb,bb,bb};
      acc[0][i] = c; acc[1][i] = c;
    }
    #pragma unroll
    for (int ks = 0; ks < 8; ks++){
      short8 a0 = lda(src, 0, ks, lane);
      short8 a1 = lda(src, 1, ks, lane);
      #pragma unroll
      for (int i = 0; i < 2; i++){
        short8 bv = ldb(W, nh*4 + ic*2 + i, ks, lane);
        acc[0][i] = mfma16(a0, bv, acc[0][i]);
        acc[1][i] = mfma16(a1, bv, acc[1][i]);
      }
    }
    #pragma unroll
    for (int m = 0; m < 2; m++){
      #pragma unroll
      for (int i = 0; i < 2; i++){
        float qv = sQ[(nh*4 + ic*2 + i)*16 + cl];
        p[m][0] += acc[m][i][0]*qv;
        p[m][1] += acc[m][i][1]*qv;
        p[m][2] += acc[m][i][2]*qv;
        p[m][3] += acc[m][i][3]*qv;
      }
    }
    __builtin_amdgcn_sched_barrier(0);
  }
  #pragma unroll
  for (int m = 0; m < 2; m++){
    int rowb = m*16 + kg*4;
    #pragma unroll
    for (int r = 0; r < 4; r++){
      float v = p[m][r];
      v += __shfl_xor(v, 1, 16);
      v += __shfl_xor(v, 2, 16);
      v += __shfl_xor(v, 4, 16);
      v += __shfl_xor(v, 8, 16);
      if (cl == 0) sS[rowb + r][nh] = v;
    }
  }
}

// V = vin @ v_proj + vb -> dst ; CHUNKED 2x
__device__ __forceinline__ void gemm3_store(const uint16_t* src, const uint16_t* W, const float* bs,
                                            uint16_t* dst, int lane, int nh){
  const int cl = lane & 15, kg = lane >> 4;
  #pragma unroll
  for (int ic = 0; ic < 2; ic++){
    f32x4 acc[2][2];
    #pragma unroll
    for (int i = 0; i < 2; i++){
      float bb = bs[(nh*4 + ic*2 + i)*16 + cl];
      f32x4 c = {bb,bb,bb,bb};
      acc[0][i] = c; acc[1][i] = c;
    }
    #pragma unroll
    for (int ks = 0; ks < 8; ks++){
      short8 a0 = lda(src, 0, ks, lane);
      short8 a1 = lda(src, 1, ks, lane);
      #pragma unroll
      for (int i = 0; i < 2; i++){
        short8 bv = ldb(W, nh*4 + ic*2 + i, ks, lane);
        acc[0][i] = mfma16(a0, bv, acc[0][i]);
        acc[1][i] = mfma16(a1, bv, acc[1][i]);
      }
    }
    #pragma unroll
    for (int m = 0; m < 2; m++){
      int rowb = m*16 + kg*4;
      #pragma unroll
      for (int i = 0; i < 2; i++){
        int col = (nh*4 + ic*2 + i)*16 + cl;
        #pragma unroll
        for (int r = 0; r < 4; r++)
          dst[swz_off(rowb + r, col)] = f2bf(acc[m][i][r]);
      }
    }
    __builtin_amdgcn_sched_barrier(0);
  }
}

// ---------------- fused kernel: 1 block = 1 node, chunked (<=128 VGPR), 8 waves/CU ----------------
__launch_bounds__(256, 2)
__global__ void fused_kernel(const void* nodes_i, const void* edges, const void* nodes_j, const void* maskp,
                             const void* wsv, float* out)
{
  const char* ws = (const char*)wsv;
  const int* flags = (const int*)ws;
  const int fbf = flags[0], mk = flags[1];
  const uint16_t* wu = (const uint16_t*)(ws + WU_OFF);
  const float* bias = (const float*)(ws + BIAS_OFF);
  const uint16_t* W1k = wu;
  const uint16_t* W1v = wu + 65536;
  const uint16_t* W2k = wu + 131072;
  const uint16_t* W2v = wu + 262144;
  const uint16_t* KBw = wu + 393216;
  const uint16_t* VBw = wu + 458752;
  const uint16_t* QBt = wu + 524288;
  const uint16_t* WoB = wu + 589824;
  const float* b1k = bias;
  const float* b2k = bias + 256;
  const float* b1v = bias + 768;
  const float* b2v = bias + 1024;
  const float* kbb = bias + 1536;
  const float* vbb = bias + 1792;
  const float* qbb = bias + 2048;

  __shared__ __align__(16) uint16_t bufE[KI*DM];   // E -> kin
  __shared__ __align__(16) uint16_t bufXJ[KI*DM];  // nodes_j (bf16, swizzled)
  __shared__ __align__(16) uint16_t bufA[KI*DM];   // h_k -> vin
  __shared__ __align__(16) uint16_t bufB[KI*DM];   // h_v -> V
  __shared__ float sQ[DM];
  __shared__ float sNI[DM];
  __shared__ float sS[KI][4];
  __shared__ float sP[KI][4];
  __shared__ float sO[DM];

  const int tid = threadIdx.x;
  const int lane = tid & 63;
  const int nh = tid >> 6;     // wave id = N-quarter / head
  const int b = blockIdx.x;
  const int z = b >> 11;
  const int n = b & 2047;
  const long ebase = ((long)(z*NNODE + n)) * (KI*DM);
  const long nbase = ((long)(z*NNODE + n)) * DM;

  // P0: stage nodes_i row + E + xj tiles (bf16, swizzled)
  sNI[tid] = read_f(nodes_i, nbase + tid, fbf);
  if (fbf){
    const uint16_t* xp = (const uint16_t*)nodes_j;
    const uint16_t* ep = (const uint16_t*)edges;
    for (int c = tid; c < 2048; c += 256){
      int sel = c >> 10, cc = c & 1023;
      int row = cc >> 5, kc = cc & 31;
      const uint16_t* src = sel ? ep : xp;
      uint16_t* dst = sel ? bufE : bufXJ;
      short8 v = *(const short8*)(src + ebase + row*256 + kc*8);
      *(short8*)(dst + row*256 + (((kc << 3) ^ ((row & 7) << 3)))) = v;
    }
  } else {
    const float* xp = (const float*)nodes_j;
    const float* ep = (const float*)edges;
    for (int c = tid; c < 2048; c += 256){
      int sel = c >> 10, cc = c & 1023;
      int row = cc >> 5, kc = cc & 31;
      const float* src = (sel ? ep : xp) + ebase + row*256 + kc*8;
      uint16_t* dst = sel ? bufE : bufXJ;
      f32x4 x0 = *(const f32x4*)src;
      f32x4 x1 = *(const f32x4*)(src + 4);
      short8 v;
      v[0]=(short)f2bf(x0[0]); v[1]=(short)f2bf(x0[1]); v[2]=(short)f2bf(x0[2]); v[3]=(short)f2bf(x0[3]);
      v[4]=(short)f2bf(x1[0]); v[5]=(short)f2bf(x1[1]); v[6]=(short)f2bf(x1[2]); v[7]=(short)f2bf(x1[3]);
      *(short8*)(dst + row*256 + (((kc << 3) ^ ((row & 7) << 3)))) = v;
    }
  }
  __syncthreads();                               // B1

  // P1: Q projection + gemm1 K then gemm1 V (chunked)
  {
    const uint16_t* wrow = QBt + tid*256;
    float a = qbb[tid];
    for (int d = 0; d < 256; d += 8){
      short8 wv = *(const short8*)(wrow + d);
      #pragma unroll
      for (int j = 0; j < 8; j++)
        a += sNI[d + j] * bf2f((uint16_t)wv[j]);
    }
    sQ[tid] = a * 0.125f;
  }
  __builtin_amdgcn_sched_barrier(0);
  gemm1_silu(bufE, W1k, b1k, bufA, lane, nh);
  gemm1_silu(bufE, W1v, b1v, bufB, lane, nh);
  __syncthreads();                               // B2  (E dead)

  // P2: gemm2 K: kin = gamma_k*xj + beta_k -> bufE
  gemm2_film(bufA, W2k, b2k, bufXJ, bufE, lane, nh);
  __syncthreads();                               // B3  (h_k dead)

  // P3: scores(kin) ; gemm2 V: vin -> bufA
  gemm3_scores(bufE, KBw, kbb, sQ, sS, lane, nh);
  gemm2_film(bufB, W2v, b2v, bufXJ, bufA, lane, nh);
  __syncthreads();                               // B4  (h_v, xj dead)

  // P4: V = vin @ VB -> bufB ; softmax (threads 0-127)
  gemm3_store(bufA, VBw, vbb, bufB, lane, nh);
  if (tid < 128){
    int h2 = tid >> 5, k2 = tid & 31;
    long mi = (long)(z*NNODE + n)*KI + k2;
    bool mval;
    if (mk == 0)      mval = ((const int*)maskp)[mi] != 0;
    else if (mk == 1) mval = ((const unsigned char*)maskp)[mi] != 0;
    else if (mk == 2) mval = ((const uint16_t*)maskp)[mi] != 0;
    else if (mk == 4) mval = ((const int*)maskp)[mi*2] != 0;
    else              mval = ((const float*)maskp)[mi] != 0.0f;
    unsigned long long bal = __ballot(mval);
    unsigned int gm = (unsigned int)(bal >> (tid & 32));
    bool anyT = (gm != 0u);
    float s = sS[k2][h2];
    if (anyT && !mval) s = -1e30f;
    float mx = s;
    mx = fmaxf(mx, __shfl_xor(mx, 16, 32));
    mx = fmaxf(mx, __shfl_xor(mx,  8, 32));
    mx = fmaxf(mx, __shfl_xor(mx,  4, 32));
    mx = fmaxf(mx, __shfl_xor(mx,  2, 32));
    mx = fmaxf(mx, __shfl_xor(mx,  1, 32));
    float e = __expf(s - mx);
    float su = e;
    su += __shfl_xor(su, 16, 32);
    su += __shfl_xor(su,  8, 32);
    su += __shfl_xor(su,  4, 32);
    su += __shfl_xor(su,  2, 32);
    su += __shfl_xor(su,  1, 32);
    sP[k2][h2] = e / su;
  }
  __syncthreads();                               // B5

  // P5: PV: col c = tid; sO[e*4+h]
  {
    int h = tid >> 6;
    float a = 0.0f;
    #pragma unroll 4
    for (int k = 0; k < KI; k++)
      a += sP[k][h] * bf2f(bufB[swz_off(k, tid)]);
    sO[(tid & 63)*4 + h] = a;
  }
  __syncthreads();                               // B6

  // P6: out projection: y[d=tid] = sum_m sO[m] * Wo[d][m]
  {
    const uint16_t* wrow = WoB + tid*256;
    float a = 0.0f;
    for (int m8 = 0; m8 < 256; m8 += 8){
      short8 wv = *(const short8*)(wrow + m8);
      #pragma unroll
      for (int j = 0; j < 8; j++)
        a += sO[m8 + j] * bf2f((uint16_t)wv[j]);
    }
    out[nbase + tid] = a;
  }
}

extern "C" void kernel_launch(void* const* d_in, const int* in_sizes, int n_in,
                              void* d_out, int out_size, void* d_ws, size_t ws_size,
                              hipStream_t stream){
  // inputs: 0 nodes_i, 1 edges, 2 nodes_j, 3 nbr_mask, 4 fk_W1, 5 fk_b1,
  // 6 fk_W2, 7 fk_b2, 8 fv_W1, 9 fv_b1, 10 fv_W2, 11 fv_b2, 12 q_proj,
  // 13 k_proj, 14 v_proj, 15 q_bias, 16 k_bias, 17 v_bias, 18 out_W
  int* flags = (int*)d_ws;
  sniff_kernel<<<1, 256, 0, stream>>>((const uint32_t*)d_in[0], (const uint32_t*)d_in[3], flags);
  prep_kernel<<<1024, 256, 0, stream>>>(d_in[4], d_in[5], d_in[6], d_in[7],
                                        d_in[8], d_in[9], d_in[10], d_in[11],
                                        d_in[12], d_in[13], d_in[14],
                                        d_in[15], d_in[16], d_in[17],
                                        d_in[18], d_ws);
  fused_kernel<<<2*NNODE, 256, 0, stream>>>(d_in[0], d_in[1], d_in[2], d_in[3], d_ws, (float*)d_out);
}